// Round 18
// baseline (229.639 us; speedup 1.0000x reference)
//
#include <hip/hip_runtime.h>
#include <hip/hip_fp16.h>

#define IN_F 24
#define HID 64
#define NB 512      // dst buckets (node ranges)
#define NPB 256     // partition blocks (edge slices)
#define GSZ_MAX 256 // max nodes per bucket (ceil(100000/512) = 196)
#define PBUF 7168   // pair capacity per bucket in LDS (mean ~6250, +11 sigma)
#define SRC_BITS 17 // src < 100000 < 2^17; loc < 196 < 2^8

typedef unsigned int u32;

// bucket of node d:  k = floor(d*NB/n)
// node range of bucket b (exact inverse):  [ceil(b*n/NB), ceil((b+1)*n/NB))
__device__ __forceinline__ int bucket_lo(int b, int n) {
    return (int)(((long long)b * n + NB - 1) / NB);
}

// ---------------- pass 1a: per-(slice,bucket) histogram ----------------
__global__ __launch_bounds__(256) void k_pcount(const int* __restrict__ dst,
                                                u32* __restrict__ pc, int e, int n) {
    __shared__ u32 h[NB];
    for (int j = threadIdx.x; j < NB; j += 256) h[j] = 0;
    __syncthreads();
    int blk = blockIdx.x;
    long long begin = (long long)e * blk / NPB;
    long long end   = (long long)e * (blk + 1) / NPB;
    for (long long i = begin + threadIdx.x; i < end; i += 256) {
        int k = (int)((long long)dst[i] * NB / n);
        atomicAdd(&h[k], 1u);
    }
    __syncthreads();
    for (int j = threadIdx.x; j < NB; j += 256) pc[(size_t)blk * NB + j] = h[j];
}

// ---------------- pass 1b-parallel: per-column exclusive scan (NPB=256 rows) ----------------
__global__ __launch_bounds__(256) void k_pscan_a(u32* __restrict__ pc,
                                                 u32* __restrict__ colsum) {
    __shared__ u32 ps[256];
    int t = blockIdx.x;   // column (bucket)
    int tid = threadIdx.x;
    u32 v = pc[(size_t)tid * NB + t];
    ps[tid] = v;
    __syncthreads();
    for (int off = 1; off < 256; off <<= 1) {
        u32 v2 = (tid >= off) ? ps[tid - off] : 0;
        __syncthreads();
        ps[tid] += v2;
        __syncthreads();
    }
    pc[(size_t)tid * NB + t] = ps[tid] - v;   // exclusive within-column
    if (tid == 255) colsum[t] = ps[255];
}

// exclusive scan of the 512 column sums -> bucket bases
__global__ void k_pscan_b(const u32* __restrict__ colsum, u32* __restrict__ basep) {
    __shared__ u32 s[NB];
    int t = threadIdx.x;
    u32 v = colsum[t];
    s[t] = v;
    __syncthreads();
    for (int off = 1; off < NB; off <<= 1) {
        u32 v2 = (t >= off) ? s[t - off] : 0;
        __syncthreads();
        s[t] += v2;
        __syncthreads();
    }
    basep[t] = s[t] - v;
}

// ---------------- pass 1c: direct scatter of packed (loc<<17|src) into bucket order ----------------
// (measured best; staged-LDS variants regressed: R13 53us, R14 62us, vs this <=43us)
__global__ __launch_bounds__(256) void k_part(const int* __restrict__ src,
                                              const int* __restrict__ dst,
                                              const u32* __restrict__ pc,
                                              const u32* __restrict__ basep,
                                              u32* __restrict__ pairs, int e, int n) {
    __shared__ u32 cur[NB];
    int blk = (blockIdx.x & 7) * (NPB / 8) + (blockIdx.x >> 3);  // XCD-affine (perf heuristic)
    for (int j = threadIdx.x; j < NB; j += 256)
        cur[j] = pc[(size_t)blk * NB + j] + basep[j];
    __syncthreads();
    long long begin = (long long)e * blk / NPB;
    long long end   = (long long)e * (blk + 1) / NPB;
    for (long long i = begin + threadIdx.x; i < end; i += 256) {
        int d = dst[i];
        int sv = src[i];
        int k = (int)((long long)d * NB / n);
        u32 loc = (u32)(d - bucket_lo(k, n));
        u32 pos = atomicAdd(&cur[k], 1u);
        pairs[pos] = (loc << SRC_BITS) | (u32)sv;
    }
}

// ---------------- pass 2: per-bucket mini-CSR in LDS (+ fused xs f16 pack) ----------------
__global__ __launch_bounds__(256) void k_bucket(const u32* __restrict__ pairs,
                                                const u32* __restrict__ basep,
                                                const float* __restrict__ x,
                                                int* __restrict__ cnt,
                                                int* __restrict__ row_start,
                                                float* __restrict__ dinv,
                                                int* __restrict__ csr_src,
                                                __half2* __restrict__ xs2, int e, int n) {
    __shared__ u32 pbuf[PBUF];
    __shared__ u32 h[GSZ_MAX];
    __shared__ u32 cur[GSZ_MAX];
    __shared__ u32 sc[GSZ_MAX];
    __shared__ float dloc[GSZ_MAX];
    int b = blockIdx.x;
    int lo = bucket_lo(b, n);
    int hi = bucket_lo(b + 1, n);
    int gsz = hi - lo;               // <= GSZ_MAX
    u32 start = basep[b];
    u32 endp = (b + 1 < NB) ? basep[b + 1] : (u32)e;
    int nbp = (int)(endp - start);
    for (int j = threadIdx.x; j < GSZ_MAX; j += 256) h[j] = 0;
    __syncthreads();
    int stored = nbp < PBUF ? nbp : PBUF;
    for (int i = threadIdx.x; i < stored; i += 256) {
        u32 p = pairs[start + i];
        pbuf[i] = p;
        atomicAdd(&h[p >> SRC_BITS], 1u);
    }
    for (int i = PBUF + threadIdx.x; i < nbp; i += 256) {  // overflow path (rare)
        atomicAdd(&h[pairs[start + i] >> SRC_BITS], 1u);
    }
    __syncthreads();
    int t = threadIdx.x;
    u32 v = h[t];
    sc[t] = v;
    __syncthreads();
    for (int off = 1; off < 256; off <<= 1) {
        u32 v2 = (t >= off) ? sc[t - off] : 0;
        __syncthreads();
        sc[t] += v2;
        __syncthreads();
    }
    u32 excl = sc[t] - v;
    if (t < gsz) {
        float dv = rsqrtf((float)(v + 1));  // +1 self-loop
        cnt[lo + t] = (int)v;
        row_start[lo + t] = (int)(start + excl);
        dinv[lo + t] = dv;
        dloc[t] = dv;
        cur[t] = excl;
    }
    __syncthreads();
    for (int i = threadIdx.x; i < stored; i += 256) {
        u32 p = pbuf[i];
        u32 pos = atomicAdd(&cur[p >> SRC_BITS], 1u);
        csr_src[start + pos] = (int)(p & ((1u << SRC_BITS) - 1));
    }
    for (int i = PBUF + threadIdx.x; i < nbp; i += 256) {
        u32 p = pairs[start + i];
        u32 pos = atomicAdd(&cur[p >> SRC_BITS], 1u);
        csr_src[start + pos] = (int)(p & ((1u << SRC_BITS) - 1));
    }
    // fused pack: xs[i][f] = f16(x[i][f] * dinv[i]) for this bucket's nodes (contiguous)
    const float2* xf = (const float2*)(x + (long long)lo * IN_F);
    for (int i = threadIdx.x; i < gsz * 12; i += 256) {
        float2 vv = xf[i];
        float dn = dloc[i / 12];
        xs2[(long long)lo * 12 + i] = __floats2half2_rn(vv.x * dn, vv.y * dn);
    }
}

// ---------------- fused layer-1 aggregate + transform + layer-2 lin (barrier-free) ----------------
// Phase A: 16-lane groups (12 active) gather xs rows, unroll-8 -> ax/ay registers.
// Phase B: shuffle-broadcast agg feats within the group (NO LDS round-trip, NO barrier):
//          4 hidden feats/lane, relu, W2 dot, 16-lane shuffle reduce -> zs.
// Removing the A->B __syncthreads decouples waves: straggler set is 4 nodes (wave),
// not 16 (block) — degree-imbalance cost drops from ~1.7x to ~1.3x.
__global__ __launch_bounds__(256) void k_agg_hz(const float* __restrict__ x,
                                                const __half2* __restrict__ xs2,
                                                const float* __restrict__ dinv,
                                                const int* __restrict__ row_start,
                                                const int* __restrict__ cnt,
                                                const int* __restrict__ csr_src,
                                                const float* __restrict__ W1,
                                                const float* __restrict__ b1,
                                                const float* __restrict__ W2,
                                                float* __restrict__ zs, int n) {
    __shared__ float w[IN_F * HID];   // k-major: w[k*64+f]
    __shared__ float w2s[HID];
    __shared__ float b1s[HID];
    for (int j = threadIdx.x; j < IN_F * HID; j += 256) w[j] = W1[j];
    if (threadIdx.x < HID) { w2s[threadIdx.x] = W2[threadIdx.x]; b1s[threadIdx.x] = b1[threadIdx.x]; }
    __syncthreads();   // weights only; no further barriers
    int g = threadIdx.x >> 4;
    int f2 = threadIdx.x & 15;
    int node = blockIdx.x * 16 + g;
    if (node >= n) return;
    float dn = dinv[node];
    // ---- Phase A: gather-aggregate into registers (lanes 0..11 of each group) ----
    float ax = 0.0f, ay = 0.0f;
    if (f2 < 12) {
        int row = row_start[node];
        int c = cnt[node];
        int j = 0;
        for (; j + 8 <= c; j += 8) {
            const int* cp = csr_src + row + j;
            int s0 = cp[0], s1 = cp[1], s2 = cp[2], s3 = cp[3];
            int s4 = cp[4], s5 = cp[5], s6 = cp[6], s7 = cp[7];
            __half2 h0 = xs2[s0 * 12 + f2];
            __half2 h1 = xs2[s1 * 12 + f2];
            __half2 h2 = xs2[s2 * 12 + f2];
            __half2 h3 = xs2[s3 * 12 + f2];
            __half2 h4 = xs2[s4 * 12 + f2];
            __half2 h5 = xs2[s5 * 12 + f2];
            __half2 h6 = xs2[s6 * 12 + f2];
            __half2 h7 = xs2[s7 * 12 + f2];
            float2 f0 = __half22float2(h0), f1 = __half22float2(h1);
            float2 f2v = __half22float2(h2), f3 = __half22float2(h3);
            float2 f4 = __half22float2(h4), f5 = __half22float2(h5);
            float2 f6 = __half22float2(h6), f7 = __half22float2(h7);
            ax += (f0.x + f1.x) + (f2v.x + f3.x) + ((f4.x + f5.x) + (f6.x + f7.x));
            ay += (f0.y + f1.y) + (f2v.y + f3.y) + ((f4.y + f5.y) + (f6.y + f7.y));
        }
        for (; j < c; ++j) {
            int s = csr_src[row + j];
            float2 fv = __half22float2(xs2[s * 12 + f2]);
            ax += fv.x;
            ay += fv.y;
        }
        float sx = x[(long long)node * IN_F + 2 * f2];
        float sy = x[(long long)node * IN_F + 2 * f2 + 1];
        ax = (ax + sx * dn) * dn;
        ay = (ay + sy * dn) * dn;
    }
    // ---- Phase B: dense transform, agg feats broadcast via intra-group shuffle ----
    int fb = f2 * 4;
    float h0 = b1s[fb], h1 = b1s[fb + 1], h2 = b1s[fb + 2], h3 = b1s[fb + 3];
#pragma unroll
    for (int k = 0; k < IN_F; ++k) {
        float xv = __shfl((k & 1) ? ay : ax, k >> 1, 16);
        const float* wr = w + k * HID + fb;
        h0 += xv * wr[0];
        h1 += xv * wr[1];
        h2 += xv * wr[2];
        h3 += xv * wr[3];
    }
    float p = fmaxf(h0, 0.0f) * w2s[fb] + fmaxf(h1, 0.0f) * w2s[fb + 1]
            + fmaxf(h2, 0.0f) * w2s[fb + 2] + fmaxf(h3, 0.0f) * w2s[fb + 3];
    p += __shfl_down(p, 8, 16);
    p += __shfl_down(p, 4, 16);
    p += __shfl_down(p, 2, 16);
    p += __shfl_down(p, 1, 16);
    if (f2 == 0) zs[node] = p * dn;
}

// ---------------- layer 2 gather: 16-lane group per node ----------------
__global__ void k_out(const float* __restrict__ zs, const float* __restrict__ dinv,
                      const int* __restrict__ row_start, const int* __restrict__ cnt,
                      const int* __restrict__ csr_src, const float* __restrict__ b2,
                      float* __restrict__ out, int n) {
    int t = blockIdx.x * blockDim.x + threadIdx.x;
    int node = t >> 4;
    int lane = t & 15;
    if (node >= n) return;
    int row = row_start[node];
    int c = cnt[node];
    float v = 0.0f;
    for (int j = lane; j < c; j += 16) {
        v += zs[csr_src[row + j]];
    }
    v += __shfl_down(v, 8, 16);
    v += __shfl_down(v, 4, 16);
    v += __shfl_down(v, 2, 16);
    v += __shfl_down(v, 1, 16);
    if (lane == 0) {
        out[node] = b2[0] + dinv[node] * (zs[node] + v);
    }
}

extern "C" void kernel_launch(void* const* d_in, const int* in_sizes, int n_in,
                              void* d_out, int out_size, void* d_ws, size_t ws_size,
                              hipStream_t stream) {
    const float* x   = (const float*)d_in[0];
    const int*   ei  = (const int*)d_in[1];
    const float* W1  = (const float*)d_in[2];
    const float* b1  = (const float*)d_in[3];
    const float* W2  = (const float*)d_in[4];
    const float* b2  = (const float*)d_in[5];
    float* out = (float*)d_out;

    const int n = in_sizes[0] / IN_F;      // 100000
    const int e = in_sizes[1] / 2;         // 3200000
    const int* src = ei;
    const int* dst = ei + e;

    const int B = 256;

    // workspace layout. pairs (u32, CSR build) overlays zs (lifetimes disjoint:
    // pairs dead after k_bucket; zs born in k_agg_hz). xs written by k_bucket while
    // other blocks still read pairs -> xs OUTSIDE the overlay. aggX eliminated (fused).
    char* base = (char*)d_ws;
    u32* pairs     = (u32*)base;                        // e u32 (12.8 MB)
    float* zs      = (float*)base;                      // n f32              [overlay]
    size_t ov = ((size_t)e * 4 + 255) & ~(size_t)255;
    char* after    = base + ov;
    int* cnt       = (int*)after;
    int* row_start = cnt + n;
    int* csr_src   = row_start + n;                     // e ints (12.8 MB)
    float* dinv    = (float*)(csr_src + e);
    __half* xs     = (__half*)(dinv + n);               // n*24 f16 (4.8 MB) — NOT overlaid
    u32* pc        = (u32*)(xs + (size_t)n * IN_F);     // NPB*NB u32 (0.5 MB)
    u32* colsum    = pc + (size_t)NPB * NB;             // NB u32
    u32* basep     = colsum + NB;                       // NB u32

    // CSR build: single-read two-level bucket sort (no device-scope atomics)
    k_pcount<<<NPB, B, 0, stream>>>(dst, pc, e, n);
    k_pscan_a<<<NB, B, 0, stream>>>(pc, colsum);
    k_pscan_b<<<1, NB, 0, stream>>>(colsum, basep);
    k_part<<<NPB, B, 0, stream>>>(src, dst, pc, basep, pairs, e, n);
    k_bucket<<<NB, B, 0, stream>>>(pairs, basep, x, cnt, row_start, dinv, csr_src,
                                   (__half2*)xs, e, n);

    // fused layer-1 aggregate + transform (+ layer-2 linear) -> zs (barrier-free)
    k_agg_hz<<<(n + 15) / 16, B, 0, stream>>>(x, (const __half2*)xs, dinv,
                                              row_start, cnt, csr_src,
                                              W1, b1, W2, zs, n);

    // layer 2: gather zs (16 lanes/node)
    const long long n16 = (long long)n * 16;
    k_out<<<(int)((n16 + B - 1) / B), B, 0, stream>>>(zs, dinv, row_start, cnt, csr_src, b2, out, n);
}

// Round 19
// 226.100 us; speedup vs baseline: 1.0157x; 1.0157x over previous
//
#include <hip/hip_runtime.h>
#include <hip/hip_fp16.h>

#define IN_F 24
#define HID 64
#define NB 512      // dst buckets (node ranges)
#define NPB 256     // partition blocks (edge slices)
#define GSZ_MAX 256 // max nodes per bucket (ceil(100000/512) = 196)
#define PBUF 7168   // pair capacity per bucket in LDS (mean ~6250, +11 sigma)
#define SRC_BITS 17 // src < 100000 < 2^17; loc < 196 < 2^8
#define XSTRIDE 16  // xs row stride in half2 units (64 B = exactly one cache line)

typedef unsigned int u32;

// bucket of node d:  k = floor(d*NB/n)
// node range of bucket b (exact inverse):  [ceil(b*n/NB), ceil((b+1)*n/NB))
__device__ __forceinline__ int bucket_lo(int b, int n) {
    return (int)(((long long)b * n + NB - 1) / NB);
}

// ---------------- pass 1a: per-(slice,bucket) histogram ----------------
__global__ __launch_bounds__(256) void k_pcount(const int* __restrict__ dst,
                                                u32* __restrict__ pc, int e, int n) {
    __shared__ u32 h[NB];
    for (int j = threadIdx.x; j < NB; j += 256) h[j] = 0;
    __syncthreads();
    int blk = blockIdx.x;
    long long begin = (long long)e * blk / NPB;
    long long end   = (long long)e * (blk + 1) / NPB;
    for (long long i = begin + threadIdx.x; i < end; i += 256) {
        int k = (int)((long long)dst[i] * NB / n);
        atomicAdd(&h[k], 1u);
    }
    __syncthreads();
    for (int j = threadIdx.x; j < NB; j += 256) pc[(size_t)blk * NB + j] = h[j];
}

// ---------------- pass 1b-parallel: per-column exclusive scan (NPB=256 rows) ----------------
__global__ __launch_bounds__(256) void k_pscan_a(u32* __restrict__ pc,
                                                 u32* __restrict__ colsum) {
    __shared__ u32 ps[256];
    int t = blockIdx.x;   // column (bucket)
    int tid = threadIdx.x;
    u32 v = pc[(size_t)tid * NB + t];
    ps[tid] = v;
    __syncthreads();
    for (int off = 1; off < 256; off <<= 1) {
        u32 v2 = (tid >= off) ? ps[tid - off] : 0;
        __syncthreads();
        ps[tid] += v2;
        __syncthreads();
    }
    pc[(size_t)tid * NB + t] = ps[tid] - v;   // exclusive within-column
    if (tid == 255) colsum[t] = ps[255];
}

// exclusive scan of the 512 column sums -> bucket bases
__global__ void k_pscan_b(const u32* __restrict__ colsum, u32* __restrict__ basep) {
    __shared__ u32 s[NB];
    int t = threadIdx.x;
    u32 v = colsum[t];
    s[t] = v;
    __syncthreads();
    for (int off = 1; off < NB; off <<= 1) {
        u32 v2 = (t >= off) ? s[t - off] : 0;
        __syncthreads();
        s[t] += v2;
        __syncthreads();
    }
    basep[t] = s[t] - v;
}

// ---------------- pass 1c: direct scatter of packed (loc<<17|src) into bucket order ----------------
// (measured best; staged-LDS variants regressed: R13 53us, R14 62us, vs this <=43us)
__global__ __launch_bounds__(256) void k_part(const int* __restrict__ src,
                                              const int* __restrict__ dst,
                                              const u32* __restrict__ pc,
                                              const u32* __restrict__ basep,
                                              u32* __restrict__ pairs, int e, int n) {
    __shared__ u32 cur[NB];
    int blk = (blockIdx.x & 7) * (NPB / 8) + (blockIdx.x >> 3);  // XCD-affine (perf heuristic)
    for (int j = threadIdx.x; j < NB; j += 256)
        cur[j] = pc[(size_t)blk * NB + j] + basep[j];
    __syncthreads();
    long long begin = (long long)e * blk / NPB;
    long long end   = (long long)e * (blk + 1) / NPB;
    for (long long i = begin + threadIdx.x; i < end; i += 256) {
        int d = dst[i];
        int sv = src[i];
        int k = (int)((long long)d * NB / n);
        u32 loc = (u32)(d - bucket_lo(k, n));
        u32 pos = atomicAdd(&cur[k], 1u);
        pairs[pos] = (loc << SRC_BITS) | (u32)sv;
    }
}

// ---------------- pass 2: per-bucket mini-CSR in LDS (+ fused xs f16 pack, 64 B rows) ----------------
__global__ __launch_bounds__(256) void k_bucket(const u32* __restrict__ pairs,
                                                const u32* __restrict__ basep,
                                                const float* __restrict__ x,
                                                int* __restrict__ cnt,
                                                int* __restrict__ row_start,
                                                float* __restrict__ dinv,
                                                int* __restrict__ csr_src,
                                                __half2* __restrict__ xs2, int e, int n) {
    __shared__ u32 pbuf[PBUF];
    __shared__ u32 h[GSZ_MAX];
    __shared__ u32 cur[GSZ_MAX];
    __shared__ u32 sc[GSZ_MAX];
    __shared__ float dloc[GSZ_MAX];
    int b = blockIdx.x;
    int lo = bucket_lo(b, n);
    int hi = bucket_lo(b + 1, n);
    int gsz = hi - lo;               // <= GSZ_MAX
    u32 start = basep[b];
    u32 endp = (b + 1 < NB) ? basep[b + 1] : (u32)e;
    int nbp = (int)(endp - start);
    for (int j = threadIdx.x; j < GSZ_MAX; j += 256) h[j] = 0;
    __syncthreads();
    int stored = nbp < PBUF ? nbp : PBUF;
    for (int i = threadIdx.x; i < stored; i += 256) {
        u32 p = pairs[start + i];
        pbuf[i] = p;
        atomicAdd(&h[p >> SRC_BITS], 1u);
    }
    for (int i = PBUF + threadIdx.x; i < nbp; i += 256) {  // overflow path (rare)
        atomicAdd(&h[pairs[start + i] >> SRC_BITS], 1u);
    }
    __syncthreads();
    int t = threadIdx.x;
    u32 v = h[t];
    sc[t] = v;
    __syncthreads();
    for (int off = 1; off < 256; off <<= 1) {
        u32 v2 = (t >= off) ? sc[t - off] : 0;
        __syncthreads();
        sc[t] += v2;
        __syncthreads();
    }
    u32 excl = sc[t] - v;
    if (t < gsz) {
        float dv = rsqrtf((float)(v + 1));  // +1 self-loop
        cnt[lo + t] = (int)v;
        row_start[lo + t] = (int)(start + excl);
        dinv[lo + t] = dv;
        dloc[t] = dv;
        cur[t] = excl;
    }
    __syncthreads();
    for (int i = threadIdx.x; i < stored; i += 256) {
        u32 p = pbuf[i];
        u32 pos = atomicAdd(&cur[p >> SRC_BITS], 1u);
        csr_src[start + pos] = (int)(p & ((1u << SRC_BITS) - 1));
    }
    for (int i = PBUF + threadIdx.x; i < nbp; i += 256) {
        u32 p = pairs[start + i];
        u32 pos = atomicAdd(&cur[p >> SRC_BITS], 1u);
        csr_src[start + pos] = (int)(p & ((1u << SRC_BITS) - 1));
    }
    // fused pack (64 B padded rows): xs[i][f] = f16(x[i][f]*dinv[i]); f>=24 -> 0 pad
    for (int i = threadIdx.x; i < gsz * XSTRIDE; i += 256) {
        int nl = i >> 4;          // node-local
        int f2 = i & 15;
        __half2 o = __floats2half2_rn(0.0f, 0.0f);
        if (f2 < 12) {
            const float* xr = x + (long long)(lo + nl) * IN_F + 2 * f2;
            float dn = dloc[nl];
            o = __floats2half2_rn(xr[0] * dn, xr[1] * dn);
        }
        xs2[(long long)(lo + nl) * XSTRIDE + f2] = o;
    }
}

// ---------------- fused layer-1 aggregate + transform + layer-2 lin (barrier-free) ----------------
__global__ __launch_bounds__(256) void k_agg_hz(const float* __restrict__ x,
                                                const __half2* __restrict__ xs2,
                                                const float* __restrict__ dinv,
                                                const int* __restrict__ row_start,
                                                const int* __restrict__ cnt,
                                                const int* __restrict__ csr_src,
                                                const float* __restrict__ W1,
                                                const float* __restrict__ b1,
                                                const float* __restrict__ W2,
                                                float* __restrict__ zs, int n) {
    __shared__ float w[IN_F * HID];   // k-major: w[k*64+f]
    __shared__ float w2s[HID];
    __shared__ float b1s[HID];
    for (int j = threadIdx.x; j < IN_F * HID; j += 256) w[j] = W1[j];
    if (threadIdx.x < HID) { w2s[threadIdx.x] = W2[threadIdx.x]; b1s[threadIdx.x] = b1[threadIdx.x]; }
    __syncthreads();   // weights only; no further barriers
    int g = threadIdx.x >> 4;
    int f2 = threadIdx.x & 15;
    int node = blockIdx.x * 16 + g;
    if (node >= n) return;
    float dn = dinv[node];
    // ---- Phase A: gather-aggregate into registers (lanes 0..11 of each group) ----
    float ax = 0.0f, ay = 0.0f;
    if (f2 < 12) {
        int row = row_start[node];
        int c = cnt[node];
        int j = 0;
        for (; j + 8 <= c; j += 8) {
            const int* cp = csr_src + row + j;
            int s0 = cp[0], s1 = cp[1], s2 = cp[2], s3 = cp[3];
            int s4 = cp[4], s5 = cp[5], s6 = cp[6], s7 = cp[7];
            __half2 h0 = xs2[s0 * XSTRIDE + f2];
            __half2 h1 = xs2[s1 * XSTRIDE + f2];
            __half2 h2 = xs2[s2 * XSTRIDE + f2];
            __half2 h3 = xs2[s3 * XSTRIDE + f2];
            __half2 h4 = xs2[s4 * XSTRIDE + f2];
            __half2 h5 = xs2[s5 * XSTRIDE + f2];
            __half2 h6 = xs2[s6 * XSTRIDE + f2];
            __half2 h7 = xs2[s7 * XSTRIDE + f2];
            float2 f0 = __half22float2(h0), f1 = __half22float2(h1);
            float2 f2v = __half22float2(h2), f3 = __half22float2(h3);
            float2 f4 = __half22float2(h4), f5 = __half22float2(h5);
            float2 f6 = __half22float2(h6), f7 = __half22float2(h7);
            ax += (f0.x + f1.x) + (f2v.x + f3.x) + ((f4.x + f5.x) + (f6.x + f7.x));
            ay += (f0.y + f1.y) + (f2v.y + f3.y) + ((f4.y + f5.y) + (f6.y + f7.y));
        }
        for (; j < c; ++j) {
            int s = csr_src[row + j];
            float2 fv = __half22float2(xs2[s * XSTRIDE + f2]);
            ax += fv.x;
            ay += fv.y;
        }
        float sx = x[(long long)node * IN_F + 2 * f2];
        float sy = x[(long long)node * IN_F + 2 * f2 + 1];
        ax = (ax + sx * dn) * dn;
        ay = (ay + sy * dn) * dn;
    }
    // ---- Phase B: dense transform, agg feats broadcast via intra-group shuffle ----
    int fb = f2 * 4;
    float h0 = b1s[fb], h1 = b1s[fb + 1], h2 = b1s[fb + 2], h3 = b1s[fb + 3];
#pragma unroll
    for (int k = 0; k < IN_F; ++k) {
        float xv = __shfl((k & 1) ? ay : ax, k >> 1, 16);
        const float* wr = w + k * HID + fb;
        h0 += xv * wr[0];
        h1 += xv * wr[1];
        h2 += xv * wr[2];
        h3 += xv * wr[3];
    }
    float p = fmaxf(h0, 0.0f) * w2s[fb] + fmaxf(h1, 0.0f) * w2s[fb + 1]
            + fmaxf(h2, 0.0f) * w2s[fb + 2] + fmaxf(h3, 0.0f) * w2s[fb + 3];
    p += __shfl_down(p, 8, 16);
    p += __shfl_down(p, 4, 16);
    p += __shfl_down(p, 2, 16);
    p += __shfl_down(p, 1, 16);
    if (f2 == 0) zs[node] = p * dn;
}

// ---------------- layer 2 gather: 16-lane group per node ----------------
__global__ void k_out(const float* __restrict__ zs, const float* __restrict__ dinv,
                      const int* __restrict__ row_start, const int* __restrict__ cnt,
                      const int* __restrict__ csr_src, const float* __restrict__ b2,
                      float* __restrict__ out, int n) {
    int t = blockIdx.x * blockDim.x + threadIdx.x;
    int node = t >> 4;
    int lane = t & 15;
    if (node >= n) return;
    int row = row_start[node];
    int c = cnt[node];
    float v = 0.0f;
    for (int j = lane; j < c; j += 16) {
        v += zs[csr_src[row + j]];
    }
    v += __shfl_down(v, 8, 16);
    v += __shfl_down(v, 4, 16);
    v += __shfl_down(v, 2, 16);
    v += __shfl_down(v, 1, 16);
    if (lane == 0) {
        out[node] = b2[0] + dinv[node] * (zs[node] + v);
    }
}

extern "C" void kernel_launch(void* const* d_in, const int* in_sizes, int n_in,
                              void* d_out, int out_size, void* d_ws, size_t ws_size,
                              hipStream_t stream) {
    const float* x   = (const float*)d_in[0];
    const int*   ei  = (const int*)d_in[1];
    const float* W1  = (const float*)d_in[2];
    const float* b1  = (const float*)d_in[3];
    const float* W2  = (const float*)d_in[4];
    const float* b2  = (const float*)d_in[5];
    float* out = (float*)d_out;

    const int n = in_sizes[0] / IN_F;      // 100000
    const int e = in_sizes[1] / 2;         // 3200000
    const int* src = ei;
    const int* dst = ei + e;

    const int B = 256;

    // workspace layout. pairs (u32, CSR build) overlays zs (lifetimes disjoint).
    // xs written by k_bucket while other blocks still read pairs -> OUTSIDE the overlay.
    char* base = (char*)d_ws;
    u32* pairs     = (u32*)base;                        // e u32 (12.8 MB)
    float* zs      = (float*)base;                      // n f32              [overlay]
    size_t ov = ((size_t)e * 4 + 255) & ~(size_t)255;
    char* after    = base + ov;
    int* cnt       = (int*)after;
    int* row_start = cnt + n;
    int* csr_src   = row_start + n;                     // e ints (12.8 MB)
    float* dinv    = (float*)(csr_src + e);
    __half* xs     = (__half*)(dinv + n);               // n*32 f16 padded (6.4 MB), 64B rows
    u32* pc        = (u32*)(xs + (size_t)n * 2 * XSTRIDE);  // NPB*NB u32 (0.5 MB)
    u32* colsum    = pc + (size_t)NPB * NB;             // NB u32
    u32* basep     = colsum + NB;                       // NB u32

    // CSR build: single-read two-level bucket sort (no device-scope atomics)
    k_pcount<<<NPB, B, 0, stream>>>(dst, pc, e, n);
    k_pscan_a<<<NB, B, 0, stream>>>(pc, colsum);
    k_pscan_b<<<1, NB, 0, stream>>>(colsum, basep);
    k_part<<<NPB, B, 0, stream>>>(src, dst, pc, basep, pairs, e, n);
    k_bucket<<<NB, B, 0, stream>>>(pairs, basep, x, cnt, row_start, dinv, csr_src,
                                   (__half2*)xs, e, n);

    // fused layer-1 aggregate + transform (+ layer-2 linear) -> zs (barrier-free)
    k_agg_hz<<<(n + 15) / 16, B, 0, stream>>>(x, (const __half2*)xs, dinv,
                                              row_start, cnt, csr_src,
                                              W1, b1, W2, zs, n);

    // layer 2: gather zs (16 lanes/node)
    const long long n16 = (long long)n * 16;
    k_out<<<(int)((n16 + B - 1) / B), B, 0, stream>>>(zs, dinv, row_start, cnt, csr_src, b2, out, n);
}

// Round 20
// 220.222 us; speedup vs baseline: 1.0428x; 1.0267x over previous
//
#include <hip/hip_runtime.h>
#include <hip/hip_fp16.h>

#define IN_F 24
#define HID 64
#define NB 512      // dst buckets (node ranges)
#define NPB 256     // partition blocks (edge slices)
#define GSZ_MAX 256 // max nodes per bucket (ceil(100000/512) = 196)
#define PBUF 7168   // pair capacity per bucket in LDS (mean ~6250, +11 sigma)
#define SRC_BITS 17 // src < 100000 < 2^17; loc < 196 < 2^8

typedef unsigned int u32;

// bucket of node d:  k = floor(d*NB/n)
// node range of bucket b (exact inverse):  [ceil(b*n/NB), ceil((b+1)*n/NB))
__device__ __forceinline__ int bucket_lo(int b, int n) {
    return (int)(((long long)b * n + NB - 1) / NB);
}

// ---------------- pass 1a: per-(slice,bucket) histogram ----------------
__global__ __launch_bounds__(256) void k_pcount(const int* __restrict__ dst,
                                                u32* __restrict__ pc, int e, int n) {
    __shared__ u32 h[NB];
    for (int j = threadIdx.x; j < NB; j += 256) h[j] = 0;
    __syncthreads();
    int blk = blockIdx.x;
    long long begin = (long long)e * blk / NPB;
    long long end   = (long long)e * (blk + 1) / NPB;
    for (long long i = begin + threadIdx.x; i < end; i += 256) {
        int k = (int)((long long)dst[i] * NB / n);
        atomicAdd(&h[k], 1u);
    }
    __syncthreads();
    for (int j = threadIdx.x; j < NB; j += 256) pc[(size_t)blk * NB + j] = h[j];
}

// ---------------- pass 1b-parallel: per-column exclusive scan (NPB=256 rows) ----------------
__global__ __launch_bounds__(256) void k_pscan_a(u32* __restrict__ pc,
                                                 u32* __restrict__ colsum) {
    __shared__ u32 ps[256];
    int t = blockIdx.x;   // column (bucket)
    int tid = threadIdx.x;
    u32 v = pc[(size_t)tid * NB + t];
    ps[tid] = v;
    __syncthreads();
    for (int off = 1; off < 256; off <<= 1) {
        u32 v2 = (tid >= off) ? ps[tid - off] : 0;
        __syncthreads();
        ps[tid] += v2;
        __syncthreads();
    }
    pc[(size_t)tid * NB + t] = ps[tid] - v;   // exclusive within-column
    if (tid == 255) colsum[t] = ps[255];
}

// exclusive scan of the 512 column sums -> bucket bases
__global__ void k_pscan_b(const u32* __restrict__ colsum, u32* __restrict__ basep) {
    __shared__ u32 s[NB];
    int t = threadIdx.x;
    u32 v = colsum[t];
    s[t] = v;
    __syncthreads();
    for (int off = 1; off < NB; off <<= 1) {
        u32 v2 = (t >= off) ? s[t - off] : 0;
        __syncthreads();
        s[t] += v2;
        __syncthreads();
    }
    basep[t] = s[t] - v;
}

// ---------------- pass 1c: direct scatter of packed (loc<<17|src) into bucket order ----------------
// (measured best; staged-LDS variants regressed: R13 53us, R14 62us, vs this <=43us)
__global__ __launch_bounds__(256) void k_part(const int* __restrict__ src,
                                              const int* __restrict__ dst,
                                              const u32* __restrict__ pc,
                                              const u32* __restrict__ basep,
                                              u32* __restrict__ pairs, int e, int n) {
    __shared__ u32 cur[NB];
    int blk = (blockIdx.x & 7) * (NPB / 8) + (blockIdx.x >> 3);  // XCD-affine (perf heuristic)
    for (int j = threadIdx.x; j < NB; j += 256)
        cur[j] = pc[(size_t)blk * NB + j] + basep[j];
    __syncthreads();
    long long begin = (long long)e * blk / NPB;
    long long end   = (long long)e * (blk + 1) / NPB;
    for (long long i = begin + threadIdx.x; i < end; i += 256) {
        int d = dst[i];
        int sv = src[i];
        int k = (int)((long long)d * NB / n);
        u32 loc = (u32)(d - bucket_lo(k, n));
        u32 pos = atomicAdd(&cur[k], 1u);
        pairs[pos] = (loc << SRC_BITS) | (u32)sv;
    }
}

// ---------------- pass 2: per-bucket mini-CSR in LDS (+ fused xs f16 pack, 48 B rows) ----------------
__global__ __launch_bounds__(256) void k_bucket(const u32* __restrict__ pairs,
                                                const u32* __restrict__ basep,
                                                const float* __restrict__ x,
                                                int* __restrict__ cnt,
                                                int* __restrict__ row_start,
                                                float* __restrict__ dinv,
                                                int* __restrict__ csr_src,
                                                __half2* __restrict__ xs2, int e, int n) {
    __shared__ u32 pbuf[PBUF];
    __shared__ u32 h[GSZ_MAX];
    __shared__ u32 cur[GSZ_MAX];
    __shared__ u32 sc[GSZ_MAX];
    __shared__ float dloc[GSZ_MAX];
    int b = blockIdx.x;
    int lo = bucket_lo(b, n);
    int hi = bucket_lo(b + 1, n);
    int gsz = hi - lo;               // <= GSZ_MAX
    u32 start = basep[b];
    u32 endp = (b + 1 < NB) ? basep[b + 1] : (u32)e;
    int nbp = (int)(endp - start);
    for (int j = threadIdx.x; j < GSZ_MAX; j += 256) h[j] = 0;
    __syncthreads();
    int stored = nbp < PBUF ? nbp : PBUF;
    for (int i = threadIdx.x; i < stored; i += 256) {
        u32 p = pairs[start + i];
        pbuf[i] = p;
        atomicAdd(&h[p >> SRC_BITS], 1u);
    }
    for (int i = PBUF + threadIdx.x; i < nbp; i += 256) {  // overflow path (rare)
        atomicAdd(&h[pairs[start + i] >> SRC_BITS], 1u);
    }
    __syncthreads();
    int t = threadIdx.x;
    u32 v = h[t];
    sc[t] = v;
    __syncthreads();
    for (int off = 1; off < 256; off <<= 1) {
        u32 v2 = (t >= off) ? sc[t - off] : 0;
        __syncthreads();
        sc[t] += v2;
        __syncthreads();
    }
    u32 excl = sc[t] - v;
    if (t < gsz) {
        float dv = rsqrtf((float)(v + 1));  // +1 self-loop
        cnt[lo + t] = (int)v;
        row_start[lo + t] = (int)(start + excl);
        dinv[lo + t] = dv;
        dloc[t] = dv;
        cur[t] = excl;
    }
    __syncthreads();
    for (int i = threadIdx.x; i < stored; i += 256) {
        u32 p = pbuf[i];
        u32 pos = atomicAdd(&cur[p >> SRC_BITS], 1u);
        csr_src[start + pos] = (int)(p & ((1u << SRC_BITS) - 1));
    }
    for (int i = PBUF + threadIdx.x; i < nbp; i += 256) {
        u32 p = pairs[start + i];
        u32 pos = atomicAdd(&cur[p >> SRC_BITS], 1u);
        csr_src[start + pos] = (int)(p & ((1u << SRC_BITS) - 1));
    }
    // fused pack: xs[i][f] = f16(x[i][f] * dinv[i]) for this bucket's nodes (contiguous)
    const float2* xf = (const float2*)(x + (long long)lo * IN_F);
    for (int i = threadIdx.x; i < gsz * 12; i += 256) {
        float2 vv = xf[i];
        float dn = dloc[i / 12];
        xs2[(long long)lo * 12 + i] = __floats2half2_rn(vv.x * dn, vv.y * dn);
    }
}

// ---------------- fused layer-1 aggregate + transform + layer-2 lin (barrier-free) ----------------
// Phase A: 16-lane groups (12 active) gather xs rows; unroll-16 -> 16 outstanding
// gathers per lane chain (MLP doubled vs unroll-8: latency-bound per R18/R19 counters).
__global__ __launch_bounds__(256) void k_agg_hz(const float* __restrict__ x,
                                                const __half2* __restrict__ xs2,
                                                const float* __restrict__ dinv,
                                                const int* __restrict__ row_start,
                                                const int* __restrict__ cnt,
                                                const int* __restrict__ csr_src,
                                                const float* __restrict__ W1,
                                                const float* __restrict__ b1,
                                                const float* __restrict__ W2,
                                                float* __restrict__ zs, int n) {
    __shared__ float w[IN_F * HID];   // k-major: w[k*64+f]
    __shared__ float w2s[HID];
    __shared__ float b1s[HID];
    for (int j = threadIdx.x; j < IN_F * HID; j += 256) w[j] = W1[j];
    if (threadIdx.x < HID) { w2s[threadIdx.x] = W2[threadIdx.x]; b1s[threadIdx.x] = b1[threadIdx.x]; }
    __syncthreads();   // weights only; no further barriers
    int g = threadIdx.x >> 4;
    int f2 = threadIdx.x & 15;
    int node = blockIdx.x * 16 + g;
    if (node >= n) return;
    float dn = dinv[node];
    // ---- Phase A: gather-aggregate into registers (lanes 0..11 of each group) ----
    float ax = 0.0f, ay = 0.0f;
    if (f2 < 12) {
        int row = row_start[node];
        int c = cnt[node];
        int j = 0;
        for (; j + 16 <= c; j += 16) {
            const int* cp = csr_src + row + j;
            int s0 = cp[0], s1 = cp[1], s2 = cp[2], s3 = cp[3];
            int s4 = cp[4], s5 = cp[5], s6 = cp[6], s7 = cp[7];
            int s8 = cp[8], s9 = cp[9], sa = cp[10], sb = cp[11];
            int sc_ = cp[12], sd = cp[13], se = cp[14], sf = cp[15];
            __half2 h0 = xs2[s0 * 12 + f2];
            __half2 h1 = xs2[s1 * 12 + f2];
            __half2 h2 = xs2[s2 * 12 + f2];
            __half2 h3 = xs2[s3 * 12 + f2];
            __half2 h4 = xs2[s4 * 12 + f2];
            __half2 h5 = xs2[s5 * 12 + f2];
            __half2 h6 = xs2[s6 * 12 + f2];
            __half2 h7 = xs2[s7 * 12 + f2];
            __half2 h8 = xs2[s8 * 12 + f2];
            __half2 h9 = xs2[s9 * 12 + f2];
            __half2 ha = xs2[sa * 12 + f2];
            __half2 hb = xs2[sb * 12 + f2];
            __half2 hc = xs2[sc_ * 12 + f2];
            __half2 hd = xs2[sd * 12 + f2];
            __half2 he = xs2[se * 12 + f2];
            __half2 hf = xs2[sf * 12 + f2];
            float2 f0 = __half22float2(h0), f1 = __half22float2(h1);
            float2 f2v = __half22float2(h2), f3 = __half22float2(h3);
            float2 f4 = __half22float2(h4), f5 = __half22float2(h5);
            float2 f6 = __half22float2(h6), f7 = __half22float2(h7);
            float2 f8 = __half22float2(h8), f9 = __half22float2(h9);
            float2 fa = __half22float2(ha), fb = __half22float2(hb);
            float2 fc = __half22float2(hc), fd = __half22float2(hd);
            float2 fe = __half22float2(he), ff = __half22float2(hf);
            ax += ((f0.x + f1.x) + (f2v.x + f3.x)) + ((f4.x + f5.x) + (f6.x + f7.x))
                + ((f8.x + f9.x) + (fa.x + fb.x)) + ((fc.x + fd.x) + (fe.x + ff.x));
            ay += ((f0.y + f1.y) + (f2v.y + f3.y)) + ((f4.y + f5.y) + (f6.y + f7.y))
                + ((f8.y + f9.y) + (fa.y + fb.y)) + ((fc.y + fd.y) + (fe.y + ff.y));
        }
        for (; j + 8 <= c; j += 8) {
            const int* cp = csr_src + row + j;
            int s0 = cp[0], s1 = cp[1], s2 = cp[2], s3 = cp[3];
            int s4 = cp[4], s5 = cp[5], s6 = cp[6], s7 = cp[7];
            __half2 h0 = xs2[s0 * 12 + f2];
            __half2 h1 = xs2[s1 * 12 + f2];
            __half2 h2 = xs2[s2 * 12 + f2];
            __half2 h3 = xs2[s3 * 12 + f2];
            __half2 h4 = xs2[s4 * 12 + f2];
            __half2 h5 = xs2[s5 * 12 + f2];
            __half2 h6 = xs2[s6 * 12 + f2];
            __half2 h7 = xs2[s7 * 12 + f2];
            float2 f0 = __half22float2(h0), f1 = __half22float2(h1);
            float2 f2v = __half22float2(h2), f3 = __half22float2(h3);
            float2 f4 = __half22float2(h4), f5 = __half22float2(h5);
            float2 f6 = __half22float2(h6), f7 = __half22float2(h7);
            ax += (f0.x + f1.x) + (f2v.x + f3.x) + ((f4.x + f5.x) + (f6.x + f7.x));
            ay += (f0.y + f1.y) + (f2v.y + f3.y) + ((f4.y + f5.y) + (f6.y + f7.y));
        }
        for (; j < c; ++j) {
            int s = csr_src[row + j];
            float2 fv = __half22float2(xs2[s * 12 + f2]);
            ax += fv.x;
            ay += fv.y;
        }
        float sx = x[(long long)node * IN_F + 2 * f2];
        float sy = x[(long long)node * IN_F + 2 * f2 + 1];
        ax = (ax + sx * dn) * dn;
        ay = (ay + sy * dn) * dn;
    }
    // ---- Phase B: dense transform, agg feats broadcast via intra-group shuffle ----
    int fb = f2 * 4;
    float h0 = b1s[fb], h1 = b1s[fb + 1], h2 = b1s[fb + 2], h3 = b1s[fb + 3];
#pragma unroll
    for (int k = 0; k < IN_F; ++k) {
        float xv = __shfl((k & 1) ? ay : ax, k >> 1, 16);
        const float* wr = w + k * HID + fb;
        h0 += xv * wr[0];
        h1 += xv * wr[1];
        h2 += xv * wr[2];
        h3 += xv * wr[3];
    }
    float p = fmaxf(h0, 0.0f) * w2s[fb] + fmaxf(h1, 0.0f) * w2s[fb + 1]
            + fmaxf(h2, 0.0f) * w2s[fb + 2] + fmaxf(h3, 0.0f) * w2s[fb + 3];
    p += __shfl_down(p, 8, 16);
    p += __shfl_down(p, 4, 16);
    p += __shfl_down(p, 2, 16);
    p += __shfl_down(p, 1, 16);
    if (f2 == 0) zs[node] = p * dn;
}

// ---------------- layer 2 gather: 16-lane group per node ----------------
__global__ void k_out(const float* __restrict__ zs, const float* __restrict__ dinv,
                      const int* __restrict__ row_start, const int* __restrict__ cnt,
                      const int* __restrict__ csr_src, const float* __restrict__ b2,
                      float* __restrict__ out, int n) {
    int t = blockIdx.x * blockDim.x + threadIdx.x;
    int node = t >> 4;
    int lane = t & 15;
    if (node >= n) return;
    int row = row_start[node];
    int c = cnt[node];
    float v = 0.0f;
    for (int j = lane; j < c; j += 16) {
        v += zs[csr_src[row + j]];
    }
    v += __shfl_down(v, 8, 16);
    v += __shfl_down(v, 4, 16);
    v += __shfl_down(v, 2, 16);
    v += __shfl_down(v, 1, 16);
    if (lane == 0) {
        out[node] = b2[0] + dinv[node] * (zs[node] + v);
    }
}

extern "C" void kernel_launch(void* const* d_in, const int* in_sizes, int n_in,
                              void* d_out, int out_size, void* d_ws, size_t ws_size,
                              hipStream_t stream) {
    const float* x   = (const float*)d_in[0];
    const int*   ei  = (const int*)d_in[1];
    const float* W1  = (const float*)d_in[2];
    const float* b1  = (const float*)d_in[3];
    const float* W2  = (const float*)d_in[4];
    const float* b2  = (const float*)d_in[5];
    float* out = (float*)d_out;

    const int n = in_sizes[0] / IN_F;      // 100000
    const int e = in_sizes[1] / 2;         // 3200000
    const int* src = ei;
    const int* dst = ei + e;

    const int B = 256;

    // workspace layout. pairs (u32, CSR build) overlays zs (lifetimes disjoint).
    // xs written by k_bucket while other blocks still read pairs -> OUTSIDE the overlay.
    char* base = (char*)d_ws;
    u32* pairs     = (u32*)base;                        // e u32 (12.8 MB)
    float* zs      = (float*)base;                      // n f32              [overlay]
    size_t ov = ((size_t)e * 4 + 255) & ~(size_t)255;
    char* after    = base + ov;
    int* cnt       = (int*)after;
    int* row_start = cnt + n;
    int* csr_src   = row_start + n;                     // e ints (12.8 MB)
    float* dinv    = (float*)(csr_src + e);
    __half* xs     = (__half*)(dinv + n);               // n*24 f16 (4.8 MB), 48 B rows
    u32* pc        = (u32*)(xs + (size_t)n * IN_F);     // NPB*NB u32 (0.5 MB)
    u32* colsum    = pc + (size_t)NPB * NB;             // NB u32
    u32* basep     = colsum + NB;                       // NB u32

    // CSR build: single-read two-level bucket sort (no device-scope atomics)
    k_pcount<<<NPB, B, 0, stream>>>(dst, pc, e, n);
    k_pscan_a<<<NB, B, 0, stream>>>(pc, colsum);
    k_pscan_b<<<1, NB, 0, stream>>>(colsum, basep);
    k_part<<<NPB, B, 0, stream>>>(src, dst, pc, basep, pairs, e, n);
    k_bucket<<<NB, B, 0, stream>>>(pairs, basep, x, cnt, row_start, dinv, csr_src,
                                   (__half2*)xs, e, n);

    // fused layer-1 aggregate + transform (+ layer-2 linear) -> zs (barrier-free)
    k_agg_hz<<<(n + 15) / 16, B, 0, stream>>>(x, (const __half2*)xs, dinv,
                                              row_start, cnt, csr_src,
                                              W1, b1, W2, zs, n);

    // layer 2: gather zs (16 lanes/node)
    const long long n16 = (long long)n * 16;
    k_out<<<(int)((n16 + B - 1) / B), B, 0, stream>>>(zs, dinv, row_start, cnt, csr_src, b2, out, n);
}